// Round 1
// baseline (202.404 us; speedup 1.0000x reference)
//
#include <hip/hip_runtime.h>

#define E_EDGES 320000
#define HID 128
#define K3 384
#define NR 16
#define TILE_E 64
#define NTILES (E_EDGES / TILE_E)
#define HS 392   // padded K stride (bf16 elems) for h and Wt
#define RS 24    // padded NR stride

typedef float f32x16 __attribute__((ext_vector_type(16)));
typedef short short8 __attribute__((ext_vector_type(8)));

__device__ __forceinline__ unsigned short f2bf(float x) {
  union { float f; unsigned u; } v; v.f = x;
  unsigned u = v.u + 0x7fffu + ((v.u >> 16) & 1u);   // RNE
  return (unsigned short)(u >> 16);
}
__device__ __forceinline__ float bf2f(unsigned short b) {
  union { unsigned u; float f; } v; v.u = ((unsigned)b) << 16;
  return v.f;
}

__global__ __launch_bounds__(512, 2)
void edge_feat_kernel(const float* __restrict__ node_embs,
                      const int* __restrict__ eidx,
                      const float* __restrict__ ew,
                      const float* __restrict__ Wrbf0,
                      const float* __restrict__ brbf0,
                      const float* __restrict__ Wlin,
                      const float* __restrict__ blin,
                      const float* __restrict__ Wrbf1,
                      float* __restrict__ out)
{
  // LDS budget: 100352 + 50176 + 1536*2 + 3072*2 = 159744 B  (<= 163840)
  __shared__ __align__(16) unsigned short Wt[HID * HS];      // Wlin^T bf16 [col][k]
  __shared__ __align__(16) unsigned short hT[TILE_E * HS];   // h bf16 [edge][k]
  __shared__ __align__(16) unsigned short rbfb[TILE_E * RS]; // rbf bf16 [edge][r]
  __shared__ __align__(16) unsigned short w1t[HID * RS];     // Wrbf1^T bf16 [col][r]

  const int t    = threadIdx.x;
  const int lane = t & 63;
  const int w    = t >> 6;

  // ---- stage weights once per block ----
  for (int i = t; i < K3 * HID; i += 512) {
    int k = i >> 7, col = i & 127;
    Wt[col * HS + k] = f2bf(Wlin[i]);
  }
  for (int i = t; i < NR * HID; i += 512) {
    int r = i >> 7, col = i & 127;
    w1t[col * RS + r] = f2bf(Wrbf1[i]);
  }

  const int er   = w >> 2;          // edge sub-tile 0..1
  const int cc   = w & 3;           // col  sub-tile 0..3
  const int l31  = lane & 31;
  const int koff = (lane >> 5) * 8; // K-half select
  const int arow = er * 32 + l31;   // local edge row for A frag
  const int bcol = cc * 32 + l31;   // output col for B frag / D
  const float bl = blin[bcol];

  for (int tile = blockIdx.x; tile < NTILES; tile += gridDim.x) {
    const int e0 = tile * TILE_E;
    __syncthreads();  // prior tile's LDS readers done

    // ---- gathers: src -> h[:,0:128), dst -> h[:,128:256) ----
    for (int rep = 0; rep < 8; ++rep) {
      int idx   = rep * 512 + t;      // 0..4095
      int which = idx >> 11;          // 0 = src, 1 = dst
      int r2    = idx & 2047;
      int e_loc = r2 >> 5, q = r2 & 31;
      int node  = eidx[which * E_EDGES + e0 + e_loc];
      const float4 v = ((const float4*)node_embs)[node * 32 + q];
      unsigned short* p = &hT[e_loc * HS + which * 128 + q * 4];
      p[0] = f2bf(v.x); p[1] = f2bf(v.y); p[2] = f2bf(v.z); p[3] = f2bf(v.w);
    }
    // ---- Bessel rbf (f32 accuracy, stored bf16) ----
    for (int i = t; i < TILE_E * NR; i += 512) {
      int e_loc = i >> 4, r = i & 15;
      float d = ew[e0 + e_loc];
      float v = 0.63245553f * sinf(d * (float)(r + 1) * 0.62831853f) / d;
      rbfb[e_loc * RS + r] = f2bf(v);
    }
    __syncthreads();

    // ---- rbf0 = silu(rbf @ Wrbf0 + b) -> h[:,256:384) ----
    for (int rep = 0; rep < 16; ++rep) {
      int idx   = rep * 512 + t;      // 0..8191
      int e_loc = idx >> 7, col = idx & 127;
      float acc = brbf0[col];
      #pragma unroll
      for (int r = 0; r < NR; ++r)
        acc += bf2f(rbfb[e_loc * RS + r]) * Wrbf0[r * HID + col];
      float sv = acc / (1.f + __expf(-acc));
      hT[e_loc * HS + 256 + col] = f2bf(sv);
    }
    __syncthreads();

    // ---- MFMA: D[64e x 128c] = h @ Wlin ; sacc = rbf @ Wrbf1 ----
    f32x16 acc  = {0,0,0,0,0,0,0,0,0,0,0,0,0,0,0,0};
    f32x16 sacc = {0,0,0,0,0,0,0,0,0,0,0,0,0,0,0,0};
    #pragma unroll
    for (int ks = 0; ks < K3 / 16; ++ks) {
      short8 a = *(const short8*)&hT[arow * HS + ks * 16 + koff];
      short8 b = *(const short8*)&Wt[bcol * HS + ks * 16 + koff];
      acc = __builtin_amdgcn_mfma_f32_32x32x16_bf16(a, b, acc, 0, 0, 0);
    }
    {
      short8 ra = *(const short8*)&rbfb[arow * RS + koff];
      short8 rb = *(const short8*)&w1t[bcol * RS + koff];
      sacc = __builtin_amdgcn_mfma_f32_32x32x16_bf16(ra, rb, sacc, 0, 0, 0);
    }

    // ---- epilogue: bias + silu, e2 = s * e1, coalesced f32 stores ----
    #pragma unroll
    for (int i = 0; i < 16; ++i) {
      int row   = (i & 3) + 8 * (i >> 2) + 4 * (lane >> 5);
      int e_loc = er * 32 + row;
      float x  = acc[i] + bl;
      float e1 = x / (1.f + __expf(-x));
      float e2 = sacc[i] * e1;
      long gi = (long)(e0 + e_loc) * HID + bcol;
      out[gi] = e1;
      out[(long)E_EDGES * HID + gi] = e2;
    }
  }
}

extern "C" void kernel_launch(void* const* d_in, const int* in_sizes, int n_in,
                              void* d_out, int out_size, void* d_ws, size_t ws_size,
                              hipStream_t stream) {
  const float* node_embs = (const float*)d_in[0];
  const int*   eidx      = (const int*)d_in[1];
  const float* ew        = (const float*)d_in[2];
  const float* Wrbf0     = (const float*)d_in[3];
  const float* brbf0     = (const float*)d_in[4];
  const float* Wlin      = (const float*)d_in[5];
  const float* blin      = (const float*)d_in[6];
  const float* Wrbf1     = (const float*)d_in[7];
  float* out = (float*)d_out;

  edge_feat_kernel<<<256, 512, 0, stream>>>(node_embs, eidx, ew, Wrbf0, brbf0,
                                            Wlin, blin, Wrbf1, out);
}

// Round 2
// 137.234 us; speedup vs baseline: 1.4749x; 1.4749x over previous
//
#include <hip/hip_runtime.h>

#define E_EDGES 320000
#define HID 128
#define K3 384
#define NR 16
#define TILE_E 64
#define NTILES (E_EDGES / TILE_E)
#define HS 392   // padded K stride (bf16 elems) for h and Wt
#define RS 24    // padded NR stride

typedef float f32x16 __attribute__((ext_vector_type(16)));
typedef short short8 __attribute__((ext_vector_type(8)));

__device__ __forceinline__ unsigned short f2bf(float x) {
  union { float f; unsigned u; } v; v.f = x;
  unsigned u = v.u + 0x7fffu + ((v.u >> 16) & 1u);   // RNE
  return (unsigned short)(u >> 16);
}
// pack two f32 -> (bf16(a) | bf16(b)<<16)
__device__ __forceinline__ unsigned pk2(float a, float b) {
  union { float f; unsigned u; } va, vb; va.f = a; vb.f = b;
  unsigned ua = va.u + 0x7fffu + ((va.u >> 16) & 1u);
  unsigned ub = vb.u + 0x7fffu + ((vb.u >> 16) & 1u);
  return (ua >> 16) | (ub & 0xffff0000u);
}

__global__ __launch_bounds__(512, 2)
void edge_feat_kernel(const float* __restrict__ node_embs,
                      const int* __restrict__ eidx,
                      const float* __restrict__ ew,
                      const float* __restrict__ Wrbf0,
                      const float* __restrict__ brbf0,
                      const float* __restrict__ Wlin,
                      const float* __restrict__ blin,
                      const float* __restrict__ Wrbf1,
                      float* __restrict__ out)
{
  // LDS: 100352 + 50176 + 3072 = 153600 B (<= 163840)
  __shared__ __align__(16) unsigned short Wt[HID * HS];      // Wlin^T bf16 [col][k]
  __shared__ __align__(16) unsigned short hT[TILE_E * HS];   // h bf16 [edge][k]
  __shared__ __align__(16) unsigned short rbfb[TILE_E * RS]; // rbf bf16 [edge][r]

  const int t    = threadIdx.x;
  const int lane = t & 63;
  const int w    = t >> 6;

  // ---- stage Wlin^T once per block ----
  for (int i = t; i < K3 * HID; i += 512) {
    int k = i >> 7, col = i & 127;
    Wt[col * HS + k] = f2bf(Wlin[i]);
  }

  const int er   = w >> 2;          // edge sub-tile 0..1
  const int cc   = w & 3;           // col  sub-tile 0..3
  const int l31  = lane & 31;
  const int hi   = lane >> 5;
  const int koff = hi * 8;          // K-half select
  const int arow = er * 32 + l31;   // local edge row for A frag
  const int bcol = cc * 32 + l31;   // output col for B frag / D
  const float bl = blin[bcol];
  const float b0 = brbf0[bcol];

  // per-wave B fragments for the two 16-K GEMMs (held in registers)
  short8 w0f, w1f;
  #pragma unroll
  for (int j = 0; j < 8; ++j) {
    w0f[j] = (short)f2bf(Wrbf0[(koff + j) * HID + bcol]);
    w1f[j] = (short)f2bf(Wrbf1[(koff + j) * HID + bcol]);
  }

  for (int tile = blockIdx.x; tile < NTILES; tile += gridDim.x) {
    const int e0 = tile * TILE_E;
    __syncthreads();  // prior tile's LDS readers done

    // ---- gathers: src -> h[:,0:128), dst -> h[:,128:256), packed bf16 ----
    #pragma unroll
    for (int rep = 0; rep < 8; ++rep) {
      int idx   = rep * 512 + t;      // 0..4095
      int which = idx >> 11;          // 0 = src, 1 = dst
      int r2    = idx & 2047;
      int e_loc = r2 >> 5, q = r2 & 31;
      int node  = eidx[which * E_EDGES + e0 + e_loc];
      const float4 v = ((const float4*)node_embs)[node * 32 + q];
      uint2 pv; pv.x = pk2(v.x, v.y); pv.y = pk2(v.z, v.w);
      *(uint2*)&hT[e_loc * HS + which * 128 + q * 4] = pv;
    }
    // ---- Bessel rbf (fast sin, f32 math, bf16 store) ----
    #pragma unroll
    for (int rep = 0; rep < 2; ++rep) {
      int i = rep * 512 + t;
      int e_loc = i >> 4, r = i & 15;
      float d = ew[e0 + e_loc];
      float v = 0.63245553f * __sinf(d * (float)(r + 1) * 0.62831853f) / d;
      rbfb[e_loc * RS + r] = f2bf(v);
    }
    __syncthreads();

    // ---- rbf0 = silu(rbf @ Wrbf0 + b) via MFMA -> hT[:,256:384)
    //      sacc = rbf @ Wrbf1 (kept in regs for epilogue) ----
    f32x16 r0   = {0,0,0,0,0,0,0,0,0,0,0,0,0,0,0,0};
    f32x16 sacc = {0,0,0,0,0,0,0,0,0,0,0,0,0,0,0,0};
    short8 ra = *(const short8*)&rbfb[arow * RS + koff];
    r0   = __builtin_amdgcn_mfma_f32_32x32x16_bf16(ra, w0f, r0, 0, 0, 0);
    sacc = __builtin_amdgcn_mfma_f32_32x32x16_bf16(ra, w1f, sacc, 0, 0, 0);
    #pragma unroll
    for (int i = 0; i < 16; ++i) {
      int row = (i & 3) + 8 * (i >> 2) + 4 * hi;
      float x = r0[i] + b0;
      float s = x / (1.f + __expf(-x));
      hT[(er * 32 + row) * HS + 256 + bcol] = f2bf(s);
    }
    __syncthreads();

    // ---- main MFMA: D[64e x 128c] = h @ Wlin ----
    f32x16 acc = {0,0,0,0,0,0,0,0,0,0,0,0,0,0,0,0};
    #pragma unroll
    for (int ks = 0; ks < K3 / 16; ++ks) {
      short8 a = *(const short8*)&hT[arow * HS + ks * 16 + koff];
      short8 b = *(const short8*)&Wt[bcol * HS + ks * 16 + koff];
      acc = __builtin_amdgcn_mfma_f32_32x32x16_bf16(a, b, acc, 0, 0, 0);
    }

    // ---- epilogue: bias + silu, e2 = s * e1, f32 stores ----
    #pragma unroll
    for (int i = 0; i < 16; ++i) {
      int row   = (i & 3) + 8 * (i >> 2) + 4 * hi;
      int e_loc = er * 32 + row;
      float x  = acc[i] + bl;
      float e1 = x / (1.f + __expf(-x));
      float e2 = sacc[i] * e1;
      long gi = (long)(e0 + e_loc) * HID + bcol;
      out[gi] = e1;
      out[(long)E_EDGES * HID + gi] = e2;
    }
  }
}

extern "C" void kernel_launch(void* const* d_in, const int* in_sizes, int n_in,
                              void* d_out, int out_size, void* d_ws, size_t ws_size,
                              hipStream_t stream) {
  const float* node_embs = (const float*)d_in[0];
  const int*   eidx      = (const int*)d_in[1];
  const float* ew        = (const float*)d_in[2];
  const float* Wrbf0     = (const float*)d_in[3];
  const float* brbf0     = (const float*)d_in[4];
  const float* Wlin      = (const float*)d_in[5];
  const float* blin      = (const float*)d_in[6];
  const float* Wrbf1     = (const float*)d_in[7];
  float* out = (float*)d_out;

  edge_feat_kernel<<<256, 512, 0, stream>>>(node_embs, eidx, ew, Wrbf0, brbf0,
                                            Wlin, blin, Wrbf1, out);
}

// Round 3
// 129.753 us; speedup vs baseline: 1.5599x; 1.0577x over previous
//
#include <hip/hip_runtime.h>

#define E_EDGES 320000
#define HID 128
#define K3 384
#define NR 16
#define TILE_E 64
#define NTILES (E_EDGES / TILE_E)   // 5000
#define HS 392   // padded K stride (bf16 elems), row = 784 B (16B-aligned)
#define RS 24    // padded NR stride

typedef float f32x16 __attribute__((ext_vector_type(16)));
typedef short short8 __attribute__((ext_vector_type(8)));

__device__ __forceinline__ unsigned short f2bf(float x) {
  union { float f; unsigned u; } v; v.f = x;
  unsigned u = v.u + 0x7fffu + ((v.u >> 16) & 1u);   // RNE
  return (unsigned short)(u >> 16);
}
// pack two f32 -> (bf16(a) | bf16(b)<<16)
__device__ __forceinline__ unsigned pk2(float a, float b) {
  union { float f; unsigned u; } va, vb; va.f = a; vb.f = b;
  unsigned ua = va.u + 0x7fffu + ((va.u >> 16) & 1u);
  unsigned ub = vb.u + 0x7fffu + ((vb.u >> 16) & 1u);
  return (ua >> 16) | (ub & 0xffff0000u);
}

#define BAR() asm volatile("s_waitcnt lgkmcnt(0)\n\ts_barrier" ::: "memory")

__global__ __launch_bounds__(512, 2)
void edge_feat_kernel(const float* __restrict__ node_embs,
                      const int* __restrict__ eidx,
                      const float* __restrict__ ew,
                      const float* __restrict__ Wrbf0,
                      const float* __restrict__ brbf0,
                      const float* __restrict__ Wlin,
                      const float* __restrict__ blin,
                      const float* __restrict__ Wrbf1,
                      float* __restrict__ out)
{
  // LDS: 2*64*392*2 + 2*64*24*2 = 100352 + 6144 = 106496 B
  __shared__ __align__(16) unsigned short hT[2][TILE_E * HS];
  __shared__ __align__(16) unsigned short rbfb[2][TILE_E * RS];

  const int t    = threadIdx.x;
  const int lane = t & 63;
  const int w    = t >> 6;
  const int er   = w >> 2;          // edge sub-tile 0..1
  const int cc   = w & 3;           // col  sub-tile 0..3
  const int l31  = lane & 31;
  const int hi   = lane >> 5;
  const int koff = hi * 8;
  const int arow = er * 32 + l31;
  const int bcol = cc * 32 + l31;
  const float bl = blin[bcol];
  const float b0 = brbf0[bcol];

  // ---- one-time: coalesced-stage Wlin^T into (borrowed) hT space, then
  //      pull this wave's 24 B-fragments into registers and free the LDS ----
  {
    unsigned short* WtL = &hT[0][0];  // [col][k], stride HS — 100352 B fits
    for (int i = t; i < K3 * HID; i += 512) {
      int k = i >> 7, col = i & 127;
      WtL[col * HS + k] = f2bf(Wlin[i]);
    }
    BAR();
  }
  short8 wb[24];
  #pragma unroll
  for (int ks = 0; ks < 24; ++ks)
    wb[ks] = *(const short8*)&hT[0][bcol * HS + ks * 16 + koff];
  // force the reg reads to complete before tile0 staging overwrites the space
  asm volatile("s_waitcnt lgkmcnt(0)" ::: "memory");
  __builtin_amdgcn_s_barrier();

  // small per-wave B fragments for the two K=16 GEMMs
  short8 w0f, w1f;
  #pragma unroll
  for (int j = 0; j < 8; ++j) {
    w0f[j] = (short)f2bf(Wrbf0[(koff + j) * HID + bcol]);
    w1f[j] = (short)f2bf(Wrbf1[(koff + j) * HID + bcol]);
  }

  // ---- prologue: stage tile0 into buffer 0 ----
  int tile = blockIdx.x;
  {
    #pragma unroll
    for (int rep = 0; rep < 8; ++rep) {
      int idx   = rep * 512 + t;
      int which = idx >> 11, r2 = idx & 2047;
      int e_loc = r2 >> 5, q = r2 & 31;
      int node  = eidx[which * E_EDGES + tile * TILE_E + e_loc];
      const float4 v = ((const float4*)node_embs)[node * 32 + q];
      uint2 pv; pv.x = pk2(v.x, v.y); pv.y = pk2(v.z, v.w);
      *(uint2*)&hT[0][e_loc * HS + which * 128 + q * 4] = pv;
    }
    #pragma unroll
    for (int rep = 0; rep < 2; ++rep) {
      int i = rep * 512 + t;
      int e_loc = i >> 4, r = i & 15;
      float d = ew[tile * TILE_E + e_loc];
      float v = 0.63245553f * __sinf(d * (float)(r + 1) * 0.62831853f) / d;
      rbfb[0][e_loc * RS + r] = f2bf(v);
    }
  }
  BAR();

  int cur = 0;
  for (; tile < NTILES; tile += (int)gridDim.x) {
    const int nt = tile + (int)gridDim.x;
    const bool hasnext = (nt < NTILES);
    const int e0 = tile * TILE_E;

    // ---- 1: issue next tile's gathers into registers (latency hidden) ----
    float4 g4[8];
    float dv[2];
    if (hasnext) {
      #pragma unroll
      for (int rep = 0; rep < 8; ++rep) {
        int idx   = rep * 512 + t;
        int which = idx >> 11, r2 = idx & 2047;
        int e_loc = r2 >> 5, q = r2 & 31;
        int node  = eidx[which * E_EDGES + nt * TILE_E + e_loc];
        g4[rep] = ((const float4*)node_embs)[node * 32 + q];
      }
      #pragma unroll
      for (int rep = 0; rep < 2; ++rep)
        dv[rep] = ew[nt * TILE_E + ((rep * 512 + t) >> 4)];
    }

    // ---- 2: rbf0(t) = silu(rbf@W0+b) -> hT[cur][:,256:384); sacc = rbf@W1 ----
    f32x16 r0   = {0,0,0,0,0,0,0,0,0,0,0,0,0,0,0,0};
    f32x16 sacc = {0,0,0,0,0,0,0,0,0,0,0,0,0,0,0,0};
    short8 ra = *(const short8*)&rbfb[cur][arow * RS + koff];
    r0   = __builtin_amdgcn_mfma_f32_32x32x16_bf16(ra, w0f, r0, 0, 0, 0);
    sacc = __builtin_amdgcn_mfma_f32_32x32x16_bf16(ra, w1f, sacc, 0, 0, 0);
    #pragma unroll
    for (int i = 0; i < 16; ++i) {
      int row = (i & 3) + 8 * (i >> 2) + 4 * hi;
      float x = r0[i] + b0;
      float s = x / (1.f + __expf(-x));
      hT[cur][(er * 32 + row) * HS + 256 + bcol] = f2bf(s);
    }
    BAR();   // rbf0 visible to all waves; no vmcnt drain

    // ---- 3: main MFMA over hT[cur], B from registers ----
    f32x16 acc = {0,0,0,0,0,0,0,0,0,0,0,0,0,0,0,0};
    #pragma unroll
    for (int ks = 0; ks < 24; ++ks) {
      short8 a = *(const short8*)&hT[cur][arow * HS + ks * 16 + koff];
      acc = __builtin_amdgcn_mfma_f32_32x32x16_bf16(a, wb[ks], acc, 0, 0, 0);
    }

    // ---- 4: stage tile t+1 into the other buffer (loads have landed) ----
    if (hasnext) {
      #pragma unroll
      for (int rep = 0; rep < 2; ++rep) {
        int i = rep * 512 + t;
        int e_loc = i >> 4, r = i & 15;
        float d = dv[rep];
        float v = 0.63245553f * __sinf(d * (float)(r + 1) * 0.62831853f) / d;
        rbfb[cur ^ 1][e_loc * RS + r] = f2bf(v);
      }
      #pragma unroll
      for (int rep = 0; rep < 8; ++rep) {
        int idx   = rep * 512 + t;
        int which = idx >> 11, r2 = idx & 2047;
        int e_loc = r2 >> 5, q = r2 & 31;
        uint2 pv; pv.x = pk2(g4[rep].x, g4[rep].y); pv.y = pk2(g4[rep].z, g4[rep].w);
        *(uint2*)&hT[cur ^ 1][e_loc * HS + which * 128 + q * 4] = pv;
      }
    }

    // ---- 5: epilogue: bias+silu, e2 = s*e1, nontemporal streaming stores ----
    #pragma unroll
    for (int i = 0; i < 16; ++i) {
      int row   = (i & 3) + 8 * (i >> 2) + 4 * hi;
      int e_loc = er * 32 + row;
      float x  = acc[i] + bl;
      float e1 = x / (1.f + __expf(-x));
      float e2 = sacc[i] * e1;
      long gi = (long)(e0 + e_loc) * HID + bcol;
      __builtin_nontemporal_store(e1, &out[gi]);
      __builtin_nontemporal_store(e2, &out[(long)E_EDGES * HID + gi]);
    }
    BAR();   // staging writes visible; hT[cur] readers done before t+1 overwrites
    cur ^= 1;
  }
}

extern "C" void kernel_launch(void* const* d_in, const int* in_sizes, int n_in,
                              void* d_out, int out_size, void* d_ws, size_t ws_size,
                              hipStream_t stream) {
  const float* node_embs = (const float*)d_in[0];
  const int*   eidx      = (const int*)d_in[1];
  const float* ew        = (const float*)d_in[2];
  const float* Wrbf0     = (const float*)d_in[3];
  const float* brbf0     = (const float*)d_in[4];
  const float* Wlin      = (const float*)d_in[5];
  const float* blin      = (const float*)d_in[6];
  const float* Wrbf1     = (const float*)d_in[7];
  float* out = (float*)d_out;

  edge_feat_kernel<<<256, 512, 0, stream>>>(node_embs, eidx, ew, Wrbf0, brbf0,
                                            Wlin, blin, Wrbf1, out);
}